// Round 1
// baseline (950.366 us; speedup 1.0000x reference)
//
#include <hip/hip_runtime.h>
#include <math.h>

// Problem constants (fixed by setup_inputs)
#define NTOK 16384      // B*S = 4*4096
#define SEQ  4096
#define HD   2048
#define MD   128
#define NCH  64         // number of chunks == N_SLOTS (ptr never wraps)
#define CHK  64         // chunk_size

// ---------------------------------------------------------------------------
// K0a: concat [Wq;Wk;Wv;Wg] -> Wcat (385 x 2048)
// ---------------------------------------------------------------------------
__global__ __launch_bounds__(256) void concat_kernel(
    const float* __restrict__ Wq, const float* __restrict__ Wk,
    const float* __restrict__ Wv, const float* __restrict__ Wg,
    float* __restrict__ Wcat)
{
    int i = blockIdx.x * 256 + threadIdx.x;
    if (i >= 385 * HD) return;
    int r = i >> 11;   // row (i / 2048)
    float val;
    if (r < 128)      val = Wq[i];
    else if (r < 256) val = Wk[i - 128 * HD];
    else if (r < 384) val = Wv[i - 256 * HD];
    else              val = Wg[i - 384 * HD];
    Wcat[i] = val;
}

// ---------------------------------------------------------------------------
// K0b: G = W_out^T @ W_out   (128 x 128), W_out is (2048 x 128)
// one block per row a; thread b computes G[a][b]
// ---------------------------------------------------------------------------
__global__ __launch_bounds__(128) void gmat_kernel(
    const float* __restrict__ Wo, float* __restrict__ G)
{
    __shared__ float col[HD];
    int a = blockIdx.x;
    int b = threadIdx.x;
    for (int j = b; j < HD; j += 128) col[j] = Wo[(size_t)j * MD + a];
    __syncthreads();
    float s = 0.f;
    for (int j = 0; j < HD; ++j) s = fmaf(col[j], Wo[(size_t)j * MD + b], s);
    G[a * MD + b] = s;
}

// ---------------------------------------------------------------------------
// K1: fused projection GEMM  Y = x @ Wcat^T
//   x: (16384 x 2048) row-major, Wcat: (385 x 2048) row-major (NT gemm)
//   cols 0..127 -> q, 128..255 -> k(raw), 256..383 -> v(raw), 384 -> gate(raw)
// grid: (256 row tiles, 7 col tiles), 256 threads, 64x64x32 tile, 4x4 micro
// ---------------------------------------------------------------------------
__global__ __launch_bounds__(256) void gemm_proj_kernel(
    const float* __restrict__ A, const float* __restrict__ Bm,
    float* __restrict__ q, float* __restrict__ k, float* __restrict__ v,
    float* __restrict__ g)
{
    __shared__ float As[32][68];
    __shared__ float Bs[32][68];
    const int tid  = threadIdx.x;
    const int row0 = blockIdx.x * 64;
    const int col0 = blockIdx.y * 64;
    const int tx = tid & 15, ty = tid >> 4;

    float acc[4][4] = {};

    for (int k0 = 0; k0 < HD; k0 += 32) {
        #pragma unroll
        for (int i = 0; i < 2; ++i) {
            int p  = tid + i * 256;           // 0..511
            int r  = p >> 3;                  // 0..63
            int kq = (p & 7) << 2;            // 0,4,...,28
            float4 a4 = *(const float4*)&A[(size_t)(row0 + r) * HD + k0 + kq];
            As[kq + 0][r] = a4.x; As[kq + 1][r] = a4.y;
            As[kq + 2][r] = a4.z; As[kq + 3][r] = a4.w;
            int n = col0 + r;
            float4 b4 = make_float4(0.f, 0.f, 0.f, 0.f);
            if (n < 385) b4 = *(const float4*)&Bm[(size_t)n * HD + k0 + kq];
            Bs[kq + 0][r] = b4.x; Bs[kq + 1][r] = b4.y;
            Bs[kq + 2][r] = b4.z; Bs[kq + 3][r] = b4.w;
        }
        __syncthreads();
        #pragma unroll
        for (int kk = 0; kk < 32; ++kk) {
            float4 a4 = *(const float4*)&As[kk][ty * 4];
            float4 b4 = *(const float4*)&Bs[kk][tx * 4];
            float av[4] = {a4.x, a4.y, a4.z, a4.w};
            float bv[4] = {b4.x, b4.y, b4.z, b4.w};
            #pragma unroll
            for (int im = 0; im < 4; ++im)
                #pragma unroll
                for (int jn = 0; jn < 4; ++jn)
                    acc[im][jn] = fmaf(av[im], bv[jn], acc[im][jn]);
        }
        __syncthreads();
    }

    // epilogue: whole 64-wide col tile lands in exactly one destination
    float* dst = nullptr; int cbase = 0;
    if (col0 < 128)      { dst = q; cbase = col0; }
    else if (col0 < 256) { dst = k; cbase = col0 - 128; }
    else if (col0 < 384) { dst = v; cbase = col0 - 256; }
    if (dst) {
        #pragma unroll
        for (int im = 0; im < 4; ++im) {
            int row = row0 + ty * 4 + im;
            *(float4*)&dst[(size_t)row * MD + cbase + tx * 4] =
                make_float4(acc[im][0], acc[im][1], acc[im][2], acc[im][3]);
        }
    } else {
        // gate tile: only global col 384 is valid (tx==0, jn==0)
        if (tx == 0) {
            #pragma unroll
            for (int im = 0; im < 4; ++im)
                g[row0 + ty * 4 + im] = acc[im][0];
        }
    }
}

// ---------------------------------------------------------------------------
// K1b: row-l2norm k,v in place; gate -> sigmoid(graw + b)
// one wave per row, 4 rows per block
// ---------------------------------------------------------------------------
__global__ __launch_bounds__(256) void normsig_kernel(
    float* __restrict__ k, float* __restrict__ v, float* __restrict__ w,
    const float* __restrict__ gb)
{
    int wave = threadIdx.x >> 6, lane = threadIdx.x & 63;
    int row = blockIdx.x * 4 + wave;
    size_t base = (size_t)row * MD + lane * 2;
    float2 k2 = *reinterpret_cast<float2*>(&k[base]);
    float2 v2 = *reinterpret_cast<float2*>(&v[base]);
    float ks = k2.x * k2.x + k2.y * k2.y;
    float vs = v2.x * v2.x + v2.y * v2.y;
    #pragma unroll
    for (int off = 32; off > 0; off >>= 1) {
        ks += __shfl_xor(ks, off);
        vs += __shfl_xor(vs, off);
    }
    float ki = 1.f / fmaxf(sqrtf(ks), 1e-12f);
    float vi = 1.f / fmaxf(sqrtf(vs), 1e-12f);
    k2.x *= ki; k2.y *= ki; v2.x *= vi; v2.y *= vi;
    *reinterpret_cast<float2*>(&k[base]) = k2;
    *reinterpret_cast<float2*>(&v[base]) = v2;
    if (lane == 0) {
        float gz = w[row] + gb[0];
        w[row] = 1.f / (1.f + expf(-gz));
    }
}

// ---------------------------------------------------------------------------
// K2: per-chunk aggregation (64 blocks, one per chunk)
//  k_aggT[d][t] (transposed for attn), v_agg[t][d], wstr[t]
// ---------------------------------------------------------------------------
__global__ __launch_bounds__(256) void agg_kernel(
    const float* __restrict__ kn, const float* __restrict__ vn,
    const float* __restrict__ w,
    float* __restrict__ kaT, float* __restrict__ vagg, float* __restrict__ wstr)
{
    int t   = blockIdx.x;
    int tid = threadIdx.x;
    int d = tid & 127, h = tid >> 7;
    __shared__ float s_k[128], s_v[128], s_red[256];

    float ka = 0.f, va = 0.f;
    for (int jj = 0; jj < 128; ++jj) {
        int j = h * 128 + jj;               // 0..255 token-in-chunk (b*64+c)
        int b = j >> 6, c = j & 63;
        int row = b * SEQ + t * CHK + c;
        float wv = w[row];
        ka = fmaf(wv, kn[(size_t)row * MD + d], ka);
        va = fmaf(wv, vn[(size_t)row * MD + d], va);
    }
    if (h == 1) { s_k[d] = ka; s_v[d] = va; }
    { int b = tid >> 6, c = tid & 63; s_red[tid] = w[b * SEQ + t * CHK + c]; }
    __syncthreads();
    if (h == 0) { ka += s_k[d]; va += s_v[d]; }
    for (int s = 128; s > 0; s >>= 1) {
        if (tid < s) s_red[tid] += s_red[tid + s];
        __syncthreads();
    }
    float wsum = s_red[0];
    float winv = 1.f / fmaxf(wsum, 1e-8f);
    float ku = ka * winv, vu = va * winv;
    __syncthreads();
    if (h == 0) s_red[d] = ku * ku;
    __syncthreads();
    for (int s = 64; s > 0; s >>= 1) {
        if (tid < s) s_red[tid] += s_red[tid + s];
        __syncthreads();
    }
    float kinv = 1.f / fmaxf(sqrtf(s_red[0]), 1e-12f);
    __syncthreads();
    if (h == 0) s_red[d] = vu * vu;
    __syncthreads();
    for (int s = 64; s > 0; s >>= 1) {
        if (tid < s) s_red[tid] += s_red[tid + s];
        __syncthreads();
    }
    float vinv = 1.f / fmaxf(sqrtf(s_red[0]), 1e-12f);
    if (h == 0) {
        kaT[d * NCH + t]  = ku * kinv;
        vagg[t * MD + d]  = vu * vinv;
        if (d == 0) wstr[t] = wsum * (1.f / 256.f);
    }
}

// ---------------------------------------------------------------------------
// K2b: mean_ws -> d_out[NTOK*HD]
// ---------------------------------------------------------------------------
__global__ __launch_bounds__(64) void meanws_kernel(
    const float* __restrict__ wstr, float* __restrict__ outp)
{
    int lane = threadIdx.x;
    float v = wstr[lane];
    #pragma unroll
    for (int off = 32; off > 0; off >>= 1) v += __shfl_xor(v, off);
    if (lane == 0) outp[0] = v * (1.f / 64.f);
}

// ---------------------------------------------------------------------------
// K3: causal slot attention + G-norm scale. One wave per query token.
//   chunk t attends to slots 0..t-1 (strict); t==0 -> r = 0.
//   scale = min(10 / max(sqrt(r^T G r), 1e-6), 1) applied to r.
// ---------------------------------------------------------------------------
__global__ __launch_bounds__(256) void attn_kernel(
    const float* __restrict__ q, const float* __restrict__ kaT,
    const float* __restrict__ vagg, const float* __restrict__ G,
    const float* __restrict__ logbeta, float* __restrict__ rs)
{
    __shared__ float qs[4][128];
    __shared__ float attn_s[4][64];
    __shared__ float rsh[4][128];
    int wave = threadIdx.x >> 6, lane = threadIdx.x & 63;
    int row = blockIdx.x * 4 + wave;
    int t = (row & (SEQ - 1)) >> 6;          // chunk index of this query
    float beta = expf(logbeta[0]);

    qs[wave][lane]      = q[(size_t)row * MD + lane];
    qs[wave][lane + 64] = q[(size_t)row * MD + 64 + lane];
    __syncthreads();

    float sc = -INFINITY;
    if (lane < t) {
        sc = 0.f;
        for (int d = 0; d < 128; ++d)
            sc = fmaf(qs[wave][d], kaT[d * NCH + lane], sc);
        sc *= beta;
    }
    float mx = sc;
    #pragma unroll
    for (int off = 32; off > 0; off >>= 1) mx = fmaxf(mx, __shfl_xor(mx, off));
    float e = (lane < t) ? expf(sc - mx) : 0.f;
    float ssum = e;
    #pragma unroll
    for (int off = 32; off > 0; off >>= 1) ssum += __shfl_xor(ssum, off);
    float attn = (t > 0) ? (e / ssum) : 0.f;
    attn_s[wave][lane] = attn;
    __syncthreads();

    float r0 = 0.f, r1 = 0.f;
    for (int n = 0; n < t; ++n) {
        float a = attn_s[wave][n];
        r0 = fmaf(a, vagg[n * MD + lane], r0);
        r1 = fmaf(a, vagg[n * MD + 64 + lane], r1);
    }
    rsh[wave][lane]      = r0;
    rsh[wave][lane + 64] = r1;
    __syncthreads();

    // quadratic form r^T G r (G symmetric -> coalesced reads)
    float t0 = 0.f, t1 = 0.f;
    for (int b = 0; b < 128; ++b) {
        float rb = rsh[wave][b];
        t0 = fmaf(G[b * MD + lane], rb, t0);
        t1 = fmaf(G[b * MD + 64 + lane], rb, t1);
    }
    float quad = r0 * t0 + r1 * t1;
    #pragma unroll
    for (int off = 32; off > 0; off >>= 1) quad += __shfl_xor(quad, off);
    float nrm = fmaxf(sqrtf(fmaxf(quad, 0.f)), 1e-6f);
    float scl = fminf(10.f / nrm, 1.f);
    rs[(size_t)row * MD + lane]      = r0 * scl;
    rs[(size_t)row * MD + 64 + lane] = r1 * scl;
}

// ---------------------------------------------------------------------------
// K4: out = rs @ W_out^T   (16384x128)@(2048x128)^T -> (16384x2048)
// grid (256, 32), 64x64x32 tile, 4x4 micro
// ---------------------------------------------------------------------------
__global__ __launch_bounds__(256) void gemm_out_kernel(
    const float* __restrict__ A, const float* __restrict__ Bm,
    float* __restrict__ C)
{
    __shared__ float As[32][68];
    __shared__ float Bs[32][68];
    const int tid  = threadIdx.x;
    const int row0 = blockIdx.x * 64;
    const int col0 = blockIdx.y * 64;
    const int tx = tid & 15, ty = tid >> 4;

    float acc[4][4] = {};

    for (int k0 = 0; k0 < MD; k0 += 32) {
        #pragma unroll
        for (int i = 0; i < 2; ++i) {
            int p  = tid + i * 256;
            int r  = p >> 3;
            int kq = (p & 7) << 2;
            float4 a4 = *(const float4*)&A[(size_t)(row0 + r) * MD + k0 + kq];
            As[kq + 0][r] = a4.x; As[kq + 1][r] = a4.y;
            As[kq + 2][r] = a4.z; As[kq + 3][r] = a4.w;
            float4 b4 = *(const float4*)&Bm[(size_t)(col0 + r) * MD + k0 + kq];
            Bs[kq + 0][r] = b4.x; Bs[kq + 1][r] = b4.y;
            Bs[kq + 2][r] = b4.z; Bs[kq + 3][r] = b4.w;
        }
        __syncthreads();
        #pragma unroll
        for (int kk = 0; kk < 32; ++kk) {
            float4 a4 = *(const float4*)&As[kk][ty * 4];
            float4 b4 = *(const float4*)&Bs[kk][tx * 4];
            float av[4] = {a4.x, a4.y, a4.z, a4.w};
            float bv[4] = {b4.x, b4.y, b4.z, b4.w};
            #pragma unroll
            for (int im = 0; im < 4; ++im)
                #pragma unroll
                for (int jn = 0; jn < 4; ++jn)
                    acc[im][jn] = fmaf(av[im], bv[jn], acc[im][jn]);
        }
        __syncthreads();
    }
    #pragma unroll
    for (int im = 0; im < 4; ++im) {
        int row = row0 + ty * 4 + im;
        *(float4*)&C[(size_t)row * HD + col0 + tx * 4] =
            make_float4(acc[im][0], acc[im][1], acc[im][2], acc[im][3]);
    }
}

// ---------------------------------------------------------------------------
extern "C" void kernel_launch(void* const* d_in, const int* in_sizes, int n_in,
                              void* d_out, int out_size, void* d_ws, size_t ws_size,
                              hipStream_t stream)
{
    const float* x   = (const float*)d_in[0];   // (4,4096,2048)
    const float* Wq  = (const float*)d_in[1];   // (128,2048)
    const float* Wk  = (const float*)d_in[2];
    const float* Wv  = (const float*)d_in[3];
    const float* Wo  = (const float*)d_in[4];   // (2048,128)
    const float* Wgw = (const float*)d_in[5];   // (1,2048)
    const float* Wgb = (const float*)d_in[6];   // (1,)
    const float* lb  = (const float*)d_in[7];   // (1,)
    float* out = (float*)d_out;                 // 16384*2048 + 1

    // workspace layout (floats)
    float* ws = (float*)d_ws;
    const size_t TQ = (size_t)NTOK * MD;        // 2,097,152
    float* q    = ws;
    float* kn   = q + TQ;
    float* vn   = kn + TQ;
    float* wg   = vn + TQ;        // 16384 (raw gate, then sigmoid in place)
    float* kaT  = wg + NTOK;      // 128*64
    float* vagg = kaT + MD * NCH; // 64*128
    float* wstr = vagg + NCH * MD;// 64
    float* G    = wstr + 64;      // 128*128
    float* rs   = G + MD * MD;    // 2,097,152
    float* Wcat = rs + TQ;        // 385*2048

    concat_kernel<<<dim3((385 * HD + 255) / 256), dim3(256), 0, stream>>>(
        Wq, Wk, Wv, Wgw, Wcat);
    gmat_kernel<<<dim3(128), dim3(128), 0, stream>>>(Wo, G);
    gemm_proj_kernel<<<dim3(NTOK / 64, 7), dim3(256), 0, stream>>>(
        x, Wcat, q, kn, vn, wg);
    normsig_kernel<<<dim3(NTOK / 4), dim3(256), 0, stream>>>(kn, vn, wg, Wgb);
    agg_kernel<<<dim3(NCH), dim3(256), 0, stream>>>(kn, vn, wg, kaT, vagg, wstr);
    meanws_kernel<<<dim3(1), dim3(64), 0, stream>>>(wstr, out + (size_t)NTOK * HD);
    attn_kernel<<<dim3(NTOK / 4), dim3(256), 0, stream>>>(q, kaT, vagg, G, lb, rs);
    gemm_out_kernel<<<dim3(NTOK / 64, HD / 64), dim3(256), 0, stream>>>(rs, Wo, out);
}

// Round 3
// 427.557 us; speedup vs baseline: 2.2228x; 2.2228x over previous
//
#include <hip/hip_runtime.h>
#include <math.h>
#include <stdint.h>

// Problem constants (fixed by setup_inputs)
#define NTOK 16384      // B*S = 4*4096
#define SEQ  4096
#define HD   2048
#define MD   128
#define NCH  64         // number of chunks == N_SLOTS (ptr never wraps)
#define CHK  64         // chunk_size

typedef __attribute__((ext_vector_type(8))) _Float16 half8;  // 8 fp16 = 4 VGPRs
typedef __attribute__((ext_vector_type(4))) float floatx4;   // MFMA accumulator

__device__ __forceinline__ void gload_lds16(const void* g, void* l) {
    // async global->LDS, 16B per lane; LDS dest = wave-uniform base + lane*16
    __builtin_amdgcn_global_load_lds(
        (const __attribute__((address_space(1))) unsigned int*)(uintptr_t)g,
        (__attribute__((address_space(3))) unsigned int*)(uintptr_t)l,
        16, 0, 0);
}

// ---------------------------------------------------------------------------
// K0a: convert weights to fp16: Wcath = [Wq;Wk;Wv] (384 x 2048), Woh (2048x128)
// ---------------------------------------------------------------------------
__global__ __launch_bounds__(256) void convert_w_kernel(
    const float* __restrict__ Wq, const float* __restrict__ Wk,
    const float* __restrict__ Wv, const float* __restrict__ Wo,
    _Float16* __restrict__ Wcath, _Float16* __restrict__ Woh)
{
    int i = blockIdx.x * 256 + threadIdx.x;   // 0 .. 1048575
    if (i < 384 * HD) {
        int r = i >> 11;
        float val;
        if (r < 128)      val = Wq[i];
        else if (r < 256) val = Wk[i - 128 * HD];
        else              val = Wv[i - 256 * HD];
        Wcath[i] = (_Float16)val;
    } else {
        int j = i - 384 * HD;                 // 0 .. 262143
        Woh[j] = (_Float16)Wo[j];
    }
}

// ---------------------------------------------------------------------------
// K0b: G = W_out^T @ W_out (128x128) in f32 (for the output-norm clamp)
// ---------------------------------------------------------------------------
__global__ __launch_bounds__(128) void gmat_kernel(
    const float* __restrict__ Wo, float* __restrict__ G)
{
    __shared__ float col[HD];
    int a = blockIdx.x;
    int b = threadIdx.x;
    for (int j = b; j < HD; j += 128) col[j] = Wo[(size_t)j * MD + a];
    __syncthreads();
    float s = 0.f;
    for (int j = 0; j < HD; ++j) s = fmaf(col[j], Wo[(size_t)j * MD + b], s);
    G[a * MD + b] = s;
}

// ---------------------------------------------------------------------------
// K0c: x -> fp16 (xh), fused gate matvec: wg = sigmoid(x . Wgw + b)
// one block per token row (2048 elems, 8 per thread)
// ---------------------------------------------------------------------------
__global__ __launch_bounds__(256) void convert_x_gate_kernel(
    const float* __restrict__ x, const float* __restrict__ Wgw,
    const float* __restrict__ gb,
    _Float16* __restrict__ xh, float* __restrict__ wg)
{
    int row = blockIdx.x;
    int tid = threadIdx.x;
    const float* xr = x + (size_t)row * HD;
    float4 a = *(const float4*)&xr[tid * 8];
    float4 b = *(const float4*)&xr[tid * 8 + 4];
    float4 wa = *(const float4*)&Wgw[tid * 8];
    float4 wb = *(const float4*)&Wgw[tid * 8 + 4];
    float p = a.x * wa.x + a.y * wa.y + a.z * wa.z + a.w * wa.w
            + b.x * wb.x + b.y * wb.y + b.z * wb.z + b.w * wb.w;

    half8 h;
    h[0] = (_Float16)a.x; h[1] = (_Float16)a.y;
    h[2] = (_Float16)a.z; h[3] = (_Float16)a.w;
    h[4] = (_Float16)b.x; h[5] = (_Float16)b.y;
    h[6] = (_Float16)b.z; h[7] = (_Float16)b.w;
    *(half8*)&xh[(size_t)row * HD + tid * 8] = h;

    int wave = tid >> 6, lane = tid & 63;
    #pragma unroll
    for (int off = 32; off > 0; off >>= 1) p += __shfl_xor(p, off);
    __shared__ float red[4];
    if (lane == 0) red[wave] = p;
    __syncthreads();
    if (tid == 0) {
        float t = red[0] + red[1] + red[2] + red[3] + gb[0];
        wg[row] = 1.f / (1.f + expf(-t));
    }
}

// ---------------------------------------------------------------------------
// MFMA main loop (m97 pattern): 128x128 tile, BK=32, fp16 16x16x32,
// 4 waves in 2x2, each wave 4x4 accs of 16x16. NT layout (K contiguous both).
// ---------------------------------------------------------------------------
__device__ __forceinline__ void mfma_loop(
    const _Float16* __restrict__ A, int lda,
    const _Float16* __restrict__ B, int ldb,
    int row0, int col0, int K,
    _Float16* As, _Float16* Bs, floatx4 acc[4][4])
{
    const int tid  = threadIdx.x;
    const int wave = tid >> 6, lane = tid & 63;
    const int wm = wave & 1, wn = wave >> 1;
    const int seg_r = lane >> 2;   // row within 16-row segment
    const int chunk = lane & 3;    // 8-elem (16B) chunk within row

    for (int k0 = 0; k0 < K; k0 += 32) {
        #pragma unroll
        for (int rnd = 0; rnd < 2; ++rnd) {
            int s = wave + 4 * rnd;          // segment 0..7 (16 rows each)
            int r = s * 16 + seg_r;
            gload_lds16(A + (size_t)(row0 + r) * lda + k0 + chunk * 8,
                        As + s * 512);
            gload_lds16(B + (size_t)(col0 + r) * ldb + k0 + chunk * 8,
                        Bs + s * 512);
        }
        __syncthreads();   // drains vmcnt -> LDS tiles visible
        half8 af[4], bf[4];
        #pragma unroll
        for (int i = 0; i < 4; ++i) {
            af[i] = *(const half8*)&As[(wm * 64 + i * 16 + (lane & 15)) * 32 + (lane >> 4) * 8];
            bf[i] = *(const half8*)&Bs[(wn * 64 + i * 16 + (lane & 15)) * 32 + (lane >> 4) * 8];
        }
        #pragma unroll
        for (int i = 0; i < 4; ++i)
            #pragma unroll
            for (int j = 0; j < 4; ++j)
                acc[i][j] = __builtin_amdgcn_mfma_f32_16x16x32_f16(
                    af[i], bf[j], acc[i][j], 0, 0, 0);
        __syncthreads();   // all waves done reading before next overwrite
    }
}

// ---------------------------------------------------------------------------
// K1: proj GEMM  [q|k|v] = xh @ Wcath^T  (16384 x 384), grid (128, 3)
// col tile of 128 == exactly one of q/k/v
// ---------------------------------------------------------------------------
__global__ __launch_bounds__(256) void gemm_proj_mfma(
    const _Float16* __restrict__ xh, const _Float16* __restrict__ Wcath,
    float* __restrict__ q, float* __restrict__ k, float* __restrict__ v)
{
    __shared__ _Float16 As[4096], Bs[4096];
    floatx4 acc[4][4];
    #pragma unroll
    for (int i = 0; i < 4; ++i)
        #pragma unroll
        for (int j = 0; j < 4; ++j) acc[i][j] = (floatx4){0.f, 0.f, 0.f, 0.f};

    int row0 = blockIdx.x * 128;
    int col0 = blockIdx.y * 128;
    mfma_loop(xh, HD, Wcath, HD, row0, col0, HD, As, Bs, acc);

    float* dst = (blockIdx.y == 0) ? q : ((blockIdx.y == 1) ? k : v);
    int wave = threadIdx.x >> 6, lane = threadIdx.x & 63;
    int wm = wave & 1, wn = wave >> 1;
    #pragma unroll
    for (int i = 0; i < 4; ++i) {
        int m = row0 + wm * 64 + i * 16 + (lane >> 4) * 4;
        #pragma unroll
        for (int j = 0; j < 4; ++j) {
            int c = wn * 64 + j * 16 + (lane & 15);
            #pragma unroll
            for (int r = 0; r < 4; ++r)
                dst[(size_t)(m + r) * MD + c] = acc[i][j][r];
        }
    }
}

// ---------------------------------------------------------------------------
// K1b: row-l2norm k,v in place (f32)
// ---------------------------------------------------------------------------
__global__ __launch_bounds__(256) void normsig_kernel(
    float* __restrict__ k, float* __restrict__ v)
{
    int wave = threadIdx.x >> 6, lane = threadIdx.x & 63;
    int row = blockIdx.x * 4 + wave;
    size_t base = (size_t)row * MD + lane * 2;
    float2 k2 = *reinterpret_cast<float2*>(&k[base]);
    float2 v2 = *reinterpret_cast<float2*>(&v[base]);
    float ks = k2.x * k2.x + k2.y * k2.y;
    float vs = v2.x * v2.x + v2.y * v2.y;
    #pragma unroll
    for (int off = 32; off > 0; off >>= 1) {
        ks += __shfl_xor(ks, off);
        vs += __shfl_xor(vs, off);
    }
    float ki = 1.f / fmaxf(sqrtf(ks), 1e-12f);
    float vi = 1.f / fmaxf(sqrtf(vs), 1e-12f);
    k2.x *= ki; k2.y *= ki; v2.x *= vi; v2.y *= vi;
    *reinterpret_cast<float2*>(&k[base]) = k2;
    *reinterpret_cast<float2*>(&v[base]) = v2;
}

// ---------------------------------------------------------------------------
// K2: per-chunk aggregation (64 blocks, one per chunk)
// ---------------------------------------------------------------------------
__global__ __launch_bounds__(256) void agg_kernel(
    const float* __restrict__ kn, const float* __restrict__ vn,
    const float* __restrict__ w,
    float* __restrict__ kaT, float* __restrict__ vagg, float* __restrict__ wstr)
{
    int t   = blockIdx.x;
    int tid = threadIdx.x;
    int d = tid & 127, h = tid >> 7;
    __shared__ float s_k[128], s_v[128], s_red[256];

    float ka = 0.f, va = 0.f;
    for (int jj = 0; jj < 128; ++jj) {
        int j = h * 128 + jj;
        int b = j >> 6, c = j & 63;
        int row = b * SEQ + t * CHK + c;
        float wv = w[row];
        ka = fmaf(wv, kn[(size_t)row * MD + d], ka);
        va = fmaf(wv, vn[(size_t)row * MD + d], va);
    }
    if (h == 1) { s_k[d] = ka; s_v[d] = va; }
    { int b = tid >> 6, c = tid & 63; s_red[tid] = w[b * SEQ + t * CHK + c]; }
    __syncthreads();
    if (h == 0) { ka += s_k[d]; va += s_v[d]; }
    for (int s = 128; s > 0; s >>= 1) {
        if (tid < s) s_red[tid] += s_red[tid + s];
        __syncthreads();
    }
    float wsum = s_red[0];
    float winv = 1.f / fmaxf(wsum, 1e-8f);
    float ku = ka * winv, vu = va * winv;
    __syncthreads();
    if (h == 0) s_red[d] = ku * ku;
    __syncthreads();
    for (int s = 64; s > 0; s >>= 1) {
        if (tid < s) s_red[tid] += s_red[tid + s];
        __syncthreads();
    }
    float kinv = 1.f / fmaxf(sqrtf(s_red[0]), 1e-12f);
    __syncthreads();
    if (h == 0) s_red[d] = vu * vu;
    __syncthreads();
    for (int s = 64; s > 0; s >>= 1) {
        if (tid < s) s_red[tid] += s_red[tid + s];
        __syncthreads();
    }
    float vinv = 1.f / fmaxf(sqrtf(s_red[0]), 1e-12f);
    if (h == 0) {
        kaT[d * NCH + t]  = ku * kinv;
        vagg[t * MD + d]  = vu * vinv;
        if (d == 0) wstr[t] = wsum * (1.f / 256.f);
    }
}

// ---------------------------------------------------------------------------
// K2b: mean_ws -> last element of d_out
// ---------------------------------------------------------------------------
__global__ __launch_bounds__(64) void meanws_kernel(
    const float* __restrict__ wstr, float* __restrict__ outp)
{
    int lane = threadIdx.x;
    float v = wstr[lane];
    #pragma unroll
    for (int off = 32; off > 0; off >>= 1) v += __shfl_xor(v, off);
    if (lane == 0) outp[0] = v * (1.f / 64.f);
}

// ---------------------------------------------------------------------------
// K3: causal slot attention + G-norm scale; writes r (fp16) for out GEMM
// ---------------------------------------------------------------------------
__global__ __launch_bounds__(256) void attn_kernel(
    const float* __restrict__ q, const float* __restrict__ kaT,
    const float* __restrict__ vagg, const float* __restrict__ G,
    const float* __restrict__ logbeta, _Float16* __restrict__ rsh16)
{
    __shared__ float qs[4][128];
    __shared__ float attn_s[4][64];
    __shared__ float rsh[4][128];
    int wave = threadIdx.x >> 6, lane = threadIdx.x & 63;
    int row = blockIdx.x * 4 + wave;
    int t = (row & (SEQ - 1)) >> 6;
    float beta = expf(logbeta[0]);

    qs[wave][lane]      = q[(size_t)row * MD + lane];
    qs[wave][lane + 64] = q[(size_t)row * MD + 64 + lane];
    __syncthreads();

    float sc = -INFINITY;
    if (lane < t) {
        sc = 0.f;
        for (int d = 0; d < 128; ++d)
            sc = fmaf(qs[wave][d], kaT[d * NCH + lane], sc);
        sc *= beta;
    }
    float mx = sc;
    #pragma unroll
    for (int off = 32; off > 0; off >>= 1) mx = fmaxf(mx, __shfl_xor(mx, off));
    float e = (lane < t) ? expf(sc - mx) : 0.f;
    float ssum = e;
    #pragma unroll
    for (int off = 32; off > 0; off >>= 1) ssum += __shfl_xor(ssum, off);
    float attn = (t > 0) ? (e / ssum) : 0.f;
    attn_s[wave][lane] = attn;
    __syncthreads();

    float r0 = 0.f, r1 = 0.f;
    for (int n = 0; n < t; ++n) {
        float a = attn_s[wave][n];
        r0 = fmaf(a, vagg[n * MD + lane], r0);
        r1 = fmaf(a, vagg[n * MD + 64 + lane], r1);
    }
    rsh[wave][lane]      = r0;
    rsh[wave][lane + 64] = r1;
    __syncthreads();

    float t0 = 0.f, t1 = 0.f;
    for (int b = 0; b < 128; ++b) {
        float rb = rsh[wave][b];
        t0 = fmaf(G[b * MD + lane], rb, t0);
        t1 = fmaf(G[b * MD + 64 + lane], rb, t1);
    }
    float quad = r0 * t0 + r1 * t1;
    #pragma unroll
    for (int off = 32; off > 0; off >>= 1) quad += __shfl_xor(quad, off);
    float nrm = fmaxf(sqrtf(fmaxf(quad, 0.f)), 1e-6f);
    float scl = fminf(10.f / nrm, 1.f);
    rsh16[(size_t)row * MD + lane]      = (_Float16)(r0 * scl);
    rsh16[(size_t)row * MD + 64 + lane] = (_Float16)(r1 * scl);
}

// ---------------------------------------------------------------------------
// K4: out = rsh16 @ Woh^T  (16384x128)@(2048x128)^T -> f32 (16384x2048)
// grid (128, 16)
// ---------------------------------------------------------------------------
__global__ __launch_bounds__(256) void gemm_out_mfma(
    const _Float16* __restrict__ rsh16, const _Float16* __restrict__ Woh,
    float* __restrict__ C)
{
    __shared__ _Float16 As[4096], Bs[4096];
    floatx4 acc[4][4];
    #pragma unroll
    for (int i = 0; i < 4; ++i)
        #pragma unroll
        for (int j = 0; j < 4; ++j) acc[i][j] = (floatx4){0.f, 0.f, 0.f, 0.f};

    int row0 = blockIdx.x * 128;
    int col0 = blockIdx.y * 128;
    mfma_loop(rsh16, MD, Woh, MD, row0, col0, MD, As, Bs, acc);

    int wave = threadIdx.x >> 6, lane = threadIdx.x & 63;
    int wm = wave & 1, wn = wave >> 1;
    #pragma unroll
    for (int i = 0; i < 4; ++i) {
        int m = row0 + wm * 64 + i * 16 + (lane >> 4) * 4;
        #pragma unroll
        for (int j = 0; j < 4; ++j) {
            int c = col0 + wn * 64 + j * 16 + (lane & 15);
            #pragma unroll
            for (int r = 0; r < 4; ++r)
                C[(size_t)(m + r) * HD + c] = acc[i][j][r];
        }
    }
}

// ---------------------------------------------------------------------------
extern "C" void kernel_launch(void* const* d_in, const int* in_sizes, int n_in,
                              void* d_out, int out_size, void* d_ws, size_t ws_size,
                              hipStream_t stream)
{
    const float* x   = (const float*)d_in[0];   // (4,4096,2048)
    const float* Wq  = (const float*)d_in[1];   // (128,2048)
    const float* Wk  = (const float*)d_in[2];
    const float* Wv  = (const float*)d_in[3];
    const float* Wo  = (const float*)d_in[4];   // (2048,128)
    const float* Wgw = (const float*)d_in[5];   // (1,2048)
    const float* Wgb = (const float*)d_in[6];   // (1,)
    const float* lb  = (const float*)d_in[7];   // (1,)
    float* out = (float*)d_out;                 // 16384*2048 + 1

    // workspace layout (16B-aligned throughout)
    _Float16* xh = (_Float16*)d_ws;                        // 33,554,432 fp16
    float* q    = (float*)(xh + (size_t)NTOK * HD);        // 2,097,152 f32
    float* kn   = q + (size_t)NTOK * MD;
    float* vn   = kn + (size_t)NTOK * MD;
    float* wg   = vn + (size_t)NTOK * MD;                  // 16384
    float* kaT  = wg + NTOK;                               // 8192
    float* vagg = kaT + MD * NCH;                          // 8192
    float* wstr = vagg + NCH * MD;                         // 64
    float* G    = wstr + 64;                               // 16384
    _Float16* Wcath = (_Float16*)(G + MD * MD);            // 786,432 fp16
    _Float16* Woh   = Wcath + 384 * HD;                    // 262,144 fp16
    _Float16* rsh16 = Woh + HD * MD;                       // 2,097,152 fp16

    convert_w_kernel<<<dim3(4096), dim3(256), 0, stream>>>(Wq, Wk, Wv, Wo, Wcath, Woh);
    gmat_kernel<<<dim3(128), dim3(128), 0, stream>>>(Wo, G);
    convert_x_gate_kernel<<<dim3(NTOK), dim3(256), 0, stream>>>(x, Wgw, Wgb, xh, wg);
    gemm_proj_mfma<<<dim3(NTOK / 128, 3), dim3(256), 0, stream>>>(xh, Wcath, q, kn, vn);
    normsig_kernel<<<dim3(NTOK / 4), dim3(256), 0, stream>>>(kn, vn);
    agg_kernel<<<dim3(NCH), dim3(256), 0, stream>>>(kn, vn, wg, kaT, vagg, wstr);
    meanws_kernel<<<dim3(1), dim3(64), 0, stream>>>(wstr, out + (size_t)NTOK * HD);
    attn_kernel<<<dim3(NTOK / 4), dim3(256), 0, stream>>>(q, kaT, vagg, G, lb, rsh16);
    gemm_out_mfma<<<dim3(NTOK / 128, HD / 128), dim3(256), 0, stream>>>(rsh16, Woh, out);
}

// Round 4
// 419.275 us; speedup vs baseline: 2.2667x; 1.0198x over previous
//
#include <hip/hip_runtime.h>
#include <math.h>
#include <stdint.h>

// Problem constants (fixed by setup_inputs)
#define NTOK 16384      // B*S = 4*4096
#define SEQ  4096
#define HD   2048
#define MD   128
#define NCH  64         // number of chunks == N_SLOTS (ptr never wraps)
#define CHK  64         // chunk_size

typedef __attribute__((ext_vector_type(8))) _Float16 half8;  // 8 fp16 = 4 VGPRs
typedef __attribute__((ext_vector_type(4))) float floatx4;   // MFMA accumulator

__device__ __forceinline__ void gload_lds16(const void* g, void* l) {
    // async global->LDS, 16B per lane; LDS dest = wave-uniform base + lane*16
    __builtin_amdgcn_global_load_lds(
        (const __attribute__((address_space(1))) unsigned int*)(uintptr_t)g,
        (__attribute__((address_space(3))) unsigned int*)(uintptr_t)l,
        16, 0, 0);
}

// ---------------------------------------------------------------------------
// K0a: convert weights to fp16: Wcath = [Wq;Wk;Wv] (384 x 2048), Woh (2048x128)
// ---------------------------------------------------------------------------
__global__ __launch_bounds__(256) void convert_w_kernel(
    const float* __restrict__ Wq, const float* __restrict__ Wk,
    const float* __restrict__ Wv, const float* __restrict__ Wo,
    _Float16* __restrict__ Wcath, _Float16* __restrict__ Woh)
{
    int i = blockIdx.x * 256 + threadIdx.x;   // 0 .. 1048575
    if (i < 384 * HD) {
        int r = i >> 11;
        float val;
        if (r < 128)      val = Wq[i];
        else if (r < 256) val = Wk[i - 128 * HD];
        else              val = Wv[i - 256 * HD];
        Wcath[i] = (_Float16)val;
    } else {
        int j = i - 384 * HD;                 // 0 .. 262143
        Woh[j] = (_Float16)Wo[j];
    }
}

// ---------------------------------------------------------------------------
// K0b: G = W_out^T @ W_out (128x128) in f32 (for the output-norm clamp)
// ---------------------------------------------------------------------------
__global__ __launch_bounds__(128) void gmat_kernel(
    const float* __restrict__ Wo, float* __restrict__ G)
{
    __shared__ float col[HD];
    int a = blockIdx.x;
    int b = threadIdx.x;
    for (int j = b; j < HD; j += 128) col[j] = Wo[(size_t)j * MD + a];
    __syncthreads();
    float s = 0.f;
    for (int j = 0; j < HD; ++j) s = fmaf(col[j], Wo[(size_t)j * MD + b], s);
    G[a * MD + b] = s;
}

// ---------------------------------------------------------------------------
// K1: proj GEMM with fused x->fp16 conversion and fused gate matvec.
//   [q|k|v](col tile y) = x_f32 @ Wcath^T ; y==0 blocks also produce
//   wg[row] = sigmoid(x_row . Wgw + gb).
// grid (128, 3), 256 threads, 128x128 tile, BK=32, mfma 16x16x32 f16.
// A-tile staged manually (f32 load + cvt + ds_write); B via global_load_lds.
// ---------------------------------------------------------------------------
__global__ __launch_bounds__(256) void gemm_proj_mfma(
    const float* __restrict__ x, const _Float16* __restrict__ Wcath,
    const float* __restrict__ Wgw, const float* __restrict__ gb,
    float* __restrict__ q, float* __restrict__ k, float* __restrict__ v,
    float* __restrict__ wg)
{
    __shared__ _Float16 As[4096], Bs[4096];
    floatx4 acc[4][4];
    #pragma unroll
    for (int i = 0; i < 4; ++i)
        #pragma unroll
        for (int j = 0; j < 4; ++j) acc[i][j] = (floatx4){0.f, 0.f, 0.f, 0.f};

    const int tid  = threadIdx.x;
    const int wave = tid >> 6, lane = tid & 63;
    const int wm = wave & 1, wn = wave >> 1;
    const int seg_r = lane >> 2;     // B staging: row within 16-row segment
    const int chunk = lane & 3;      // B staging: 16B chunk within row
    const int arow  = tid >> 1;      // A staging: row 0..127
    const int ahalf = tid & 1;       // A staging: which 16-col half
    const int row0 = blockIdx.x * 128;
    const int col0 = blockIdx.y * 128;
    const bool do_gate = (blockIdx.y == 0);

    float gacc = 0.f;

    for (int k0 = 0; k0 < HD; k0 += 32) {
        // ---- B tile: async global->LDS (fp16 weights) ----
        #pragma unroll
        for (int rnd = 0; rnd < 2; ++rnd) {
            int s = wave + 4 * rnd;
            int r = s * 16 + seg_r;
            gload_lds16(Wcath + (size_t)(col0 + r) * HD + k0 + chunk * 8,
                        Bs + s * 512);
        }
        // ---- A tile: f32 load -> fp16 cvt -> LDS (row arow, 16-col half) ----
        const float* ap = x + (size_t)(row0 + arow) * HD + k0 + ahalf * 16;
        float4 a0 = *(const float4*)(ap);
        float4 a1 = *(const float4*)(ap + 4);
        float4 a2 = *(const float4*)(ap + 8);
        float4 a3 = *(const float4*)(ap + 12);
        if (do_gate) {
            const float* wp = Wgw + k0 + ahalf * 16;
            float4 w0 = *(const float4*)(wp);
            float4 w1 = *(const float4*)(wp + 4);
            float4 w2 = *(const float4*)(wp + 8);
            float4 w3 = *(const float4*)(wp + 12);
            gacc += a0.x * w0.x + a0.y * w0.y + a0.z * w0.z + a0.w * w0.w
                  + a1.x * w1.x + a1.y * w1.y + a1.z * w1.z + a1.w * w1.w
                  + a2.x * w2.x + a2.y * w2.y + a2.z * w2.z + a2.w * w2.w
                  + a3.x * w3.x + a3.y * w3.y + a3.z * w3.z + a3.w * w3.w;
        }
        half8 h0, h1;
        h0[0] = (_Float16)a0.x; h0[1] = (_Float16)a0.y;
        h0[2] = (_Float16)a0.z; h0[3] = (_Float16)a0.w;
        h0[4] = (_Float16)a1.x; h0[5] = (_Float16)a1.y;
        h0[6] = (_Float16)a1.z; h0[7] = (_Float16)a1.w;
        h1[0] = (_Float16)a2.x; h1[1] = (_Float16)a2.y;
        h1[2] = (_Float16)a2.z; h1[3] = (_Float16)a2.w;
        h1[4] = (_Float16)a3.x; h1[5] = (_Float16)a3.y;
        h1[6] = (_Float16)a3.z; h1[7] = (_Float16)a3.w;
        *(half8*)&As[arow * 32 + ahalf * 16]     = h0;
        *(half8*)&As[arow * 32 + ahalf * 16 + 8] = h1;

        __syncthreads();   // drains vmcnt (B) + lgkmcnt (A writes)
        half8 af[4], bf[4];
        #pragma unroll
        for (int i = 0; i < 4; ++i) {
            af[i] = *(const half8*)&As[(wm * 64 + i * 16 + (lane & 15)) * 32 + (lane >> 4) * 8];
            bf[i] = *(const half8*)&Bs[(wn * 64 + i * 16 + (lane & 15)) * 32 + (lane >> 4) * 8];
        }
        #pragma unroll
        for (int i = 0; i < 4; ++i)
            #pragma unroll
            for (int j = 0; j < 4; ++j)
                acc[i][j] = __builtin_amdgcn_mfma_f32_16x16x32_f16(
                    af[i], bf[j], acc[i][j], 0, 0, 0);
        __syncthreads();   // all waves done reading before next overwrite
    }

    // ---- gate epilogue (y==0 only): reduce the two 16-col halves ----
    if (do_gate) {
        float g2 = gacc + __shfl_xor(gacc, 1);
        if (ahalf == 0) {
            int row = row0 + arow;
            wg[row] = 1.f / (1.f + expf(-(g2 + gb[0])));
        }
    }

    // ---- C epilogue ----
    float* dst = (blockIdx.y == 0) ? q : ((blockIdx.y == 1) ? k : v);
    #pragma unroll
    for (int i = 0; i < 4; ++i) {
        int m = row0 + wm * 64 + i * 16 + (lane >> 4) * 4;
        #pragma unroll
        for (int j = 0; j < 4; ++j) {
            int c = wn * 64 + j * 16 + (lane & 15);
            #pragma unroll
            for (int r = 0; r < 4; ++r)
                dst[(size_t)(m + r) * MD + c] = acc[i][j][r];
        }
    }
}

// ---------------------------------------------------------------------------
// K1b: row-l2norm k,v in place (f32)
// ---------------------------------------------------------------------------
__global__ __launch_bounds__(256) void normsig_kernel(
    float* __restrict__ k, float* __restrict__ v)
{
    int wave = threadIdx.x >> 6, lane = threadIdx.x & 63;
    int row = blockIdx.x * 4 + wave;
    size_t base = (size_t)row * MD + lane * 2;
    float2 k2 = *reinterpret_cast<float2*>(&k[base]);
    float2 v2 = *reinterpret_cast<float2*>(&v[base]);
    float ks = k2.x * k2.x + k2.y * k2.y;
    float vs = v2.x * v2.x + v2.y * v2.y;
    #pragma unroll
    for (int off = 32; off > 0; off >>= 1) {
        ks += __shfl_xor(ks, off);
        vs += __shfl_xor(vs, off);
    }
    float ki = 1.f / fmaxf(sqrtf(ks), 1e-12f);
    float vi = 1.f / fmaxf(sqrtf(vs), 1e-12f);
    k2.x *= ki; k2.y *= ki; v2.x *= vi; v2.y *= vi;
    *reinterpret_cast<float2*>(&k[base]) = k2;
    *reinterpret_cast<float2*>(&v[base]) = v2;
}

// ---------------------------------------------------------------------------
// K2a: per-(chunk,batch) partial aggregation. grid 256 = chunk*4 + batch.
// ---------------------------------------------------------------------------
__global__ __launch_bounds__(256) void agg_part_kernel(
    const float* __restrict__ kn, const float* __restrict__ vn,
    const float* __restrict__ w,
    float* __restrict__ kpart, float* __restrict__ vpart,
    float* __restrict__ wpart)
{
    int t = blockIdx.x >> 2, b = blockIdx.x & 3;
    int tid = threadIdx.x;
    int d = tid & 127, h = tid >> 7;
    int base_row = b * SEQ + t * CHK;

    float ka = 0.f, va = 0.f;
    for (int c = h * 32; c < h * 32 + 32; ++c) {
        int row = base_row + c;
        float wv = w[row];
        ka = fmaf(wv, kn[(size_t)row * MD + d], ka);
        va = fmaf(wv, vn[(size_t)row * MD + d], va);
    }
    __shared__ float sk[128], sv[128];
    if (h == 1) { sk[d] = ka; sv[d] = va; }
    __syncthreads();
    if (h == 0) {
        kpart[(size_t)blockIdx.x * 128 + d] = ka + sk[d];
        vpart[(size_t)blockIdx.x * 128 + d] = va + sv[d];
    }
    // w partial sum over this block's 64 tokens (first wave only)
    if (tid < 64) {
        float wv = w[base_row + tid];
        #pragma unroll
        for (int off = 32; off > 0; off >>= 1) wv += __shfl_xor(wv, off);
        if (tid == 0) wpart[blockIdx.x] = wv;
    }
}

// ---------------------------------------------------------------------------
// K2b: combine partials per chunk, normalize, emit kaT / vagg / wstr.
// grid 64, 128 threads (2 waves)
// ---------------------------------------------------------------------------
__global__ __launch_bounds__(128) void agg_combine_kernel(
    const float* __restrict__ kpart, const float* __restrict__ vpart,
    const float* __restrict__ wpart,
    float* __restrict__ kaT, float* __restrict__ vagg, float* __restrict__ wstr)
{
    int t = blockIdx.x;
    int d = threadIdx.x;              // 0..127
    int wave = d >> 6, lane = d & 63;
    float ku = 0.f, vu = 0.f;
    #pragma unroll
    for (int b = 0; b < 4; ++b) {
        ku += kpart[(size_t)(t * 4 + b) * 128 + d];
        vu += vpart[(size_t)(t * 4 + b) * 128 + d];
    }
    float wsum = wpart[t * 4] + wpart[t * 4 + 1] + wpart[t * 4 + 2] + wpart[t * 4 + 3];
    float winv = 1.f / fmaxf(wsum, 1e-8f);
    ku *= winv; vu *= winv;

    __shared__ float red[4];
    float ks = ku * ku, vs = vu * vu;
    #pragma unroll
    for (int off = 32; off > 0; off >>= 1) {
        ks += __shfl_xor(ks, off);
        vs += __shfl_xor(vs, off);
    }
    if (lane == 0) { red[wave] = ks; red[2 + wave] = vs; }
    __syncthreads();
    float kinv = 1.f / fmaxf(sqrtf(red[0] + red[1]), 1e-12f);
    float vinv = 1.f / fmaxf(sqrtf(red[2] + red[3]), 1e-12f);
    kaT[d * NCH + t] = ku * kinv;
    vagg[t * MD + d] = vu * vinv;
    if (d == 0) wstr[t] = wsum * (1.f / 256.f);
}

// ---------------------------------------------------------------------------
// K2c: mean_ws -> last element of d_out
// ---------------------------------------------------------------------------
__global__ __launch_bounds__(64) void meanws_kernel(
    const float* __restrict__ wstr, float* __restrict__ outp)
{
    int lane = threadIdx.x;
    float v = wstr[lane];
    #pragma unroll
    for (int off = 32; off > 0; off >>= 1) v += __shfl_xor(v, off);
    if (lane == 0) outp[0] = v * (1.f / 64.f);
}

// ---------------------------------------------------------------------------
// K3: causal slot attention + G-norm scale; writes r (fp16) for out GEMM
// ---------------------------------------------------------------------------
__global__ __launch_bounds__(256) void attn_kernel(
    const float* __restrict__ q, const float* __restrict__ kaT,
    const float* __restrict__ vagg, const float* __restrict__ G,
    const float* __restrict__ logbeta, _Float16* __restrict__ rsh16)
{
    __shared__ float qs[4][128];
    __shared__ float attn_s[4][64];
    __shared__ float rsh[4][128];
    int wave = threadIdx.x >> 6, lane = threadIdx.x & 63;
    int row = blockIdx.x * 4 + wave;
    int t = (row & (SEQ - 1)) >> 6;
    float beta = expf(logbeta[0]);

    qs[wave][lane]      = q[(size_t)row * MD + lane];
    qs[wave][lane + 64] = q[(size_t)row * MD + 64 + lane];
    __syncthreads();

    float sc = -INFINITY;
    if (lane < t) {
        sc = 0.f;
        for (int d = 0; d < 128; ++d)
            sc = fmaf(qs[wave][d], kaT[d * NCH + lane], sc);
        sc *= beta;
    }
    float mx = sc;
    #pragma unroll
    for (int off = 32; off > 0; off >>= 1) mx = fmaxf(mx, __shfl_xor(mx, off));
    float e = (lane < t) ? expf(sc - mx) : 0.f;
    float ssum = e;
    #pragma unroll
    for (int off = 32; off > 0; off >>= 1) ssum += __shfl_xor(ssum, off);
    float attn = (t > 0) ? (e / ssum) : 0.f;
    attn_s[wave][lane] = attn;
    __syncthreads();

    float r0 = 0.f, r1 = 0.f;
    for (int n = 0; n < t; ++n) {
        float a = attn_s[wave][n];
        r0 = fmaf(a, vagg[n * MD + lane], r0);
        r1 = fmaf(a, vagg[n * MD + 64 + lane], r1);
    }
    rsh[wave][lane]      = r0;
    rsh[wave][lane + 64] = r1;
    __syncthreads();

    float t0 = 0.f, t1 = 0.f;
    for (int b = 0; b < 128; ++b) {
        float rb = rsh[wave][b];
        t0 = fmaf(G[b * MD + lane], rb, t0);
        t1 = fmaf(G[b * MD + 64 + lane], rb, t1);
    }
    float quad = r0 * t0 + r1 * t1;
    #pragma unroll
    for (int off = 32; off > 0; off >>= 1) quad += __shfl_xor(quad, off);
    float nrm = fmaxf(sqrtf(fmaxf(quad, 0.f)), 1e-6f);
    float scl = fminf(10.f / nrm, 1.f);
    rsh16[(size_t)row * MD + lane]      = (_Float16)(r0 * scl);
    rsh16[(size_t)row * MD + 64 + lane] = (_Float16)(r1 * scl);
}

// ---------------------------------------------------------------------------
// K4: out = rsh16 @ Woh^T  (16384x128)@(2048x128)^T -> f32 (16384x2048)
// grid (128, 16)
// ---------------------------------------------------------------------------
__global__ __launch_bounds__(256) void gemm_out_mfma(
    const _Float16* __restrict__ rsh16, const _Float16* __restrict__ Woh,
    float* __restrict__ C)
{
    __shared__ _Float16 As[4096], Bs[4096];
    floatx4 acc[4][4];
    #pragma unroll
    for (int i = 0; i < 4; ++i)
        #pragma unroll
        for (int j = 0; j < 4; ++j) acc[i][j] = (floatx4){0.f, 0.f, 0.f, 0.f};

    const int tid  = threadIdx.x;
    const int wave = tid >> 6, lane = tid & 63;
    const int wm = wave & 1, wn = wave >> 1;
    const int seg_r = lane >> 2;
    const int chunk = lane & 3;
    const int row0 = blockIdx.x * 128;
    const int col0 = blockIdx.y * 128;

    for (int k0 = 0; k0 < MD; k0 += 32) {
        #pragma unroll
        for (int rnd = 0; rnd < 2; ++rnd) {
            int s = wave + 4 * rnd;
            int r = s * 16 + seg_r;
            gload_lds16(rsh16 + (size_t)(row0 + r) * MD + k0 + chunk * 8,
                        As + s * 512);
            gload_lds16(Woh + (size_t)(col0 + r) * MD + k0 + chunk * 8,
                        Bs + s * 512);
        }
        __syncthreads();
        half8 af[4], bf[4];
        #pragma unroll
        for (int i = 0; i < 4; ++i) {
            af[i] = *(const half8*)&As[(wm * 64 + i * 16 + (lane & 15)) * 32 + (lane >> 4) * 8];
            bf[i] = *(const half8*)&Bs[(wn * 64 + i * 16 + (lane & 15)) * 32 + (lane >> 4) * 8];
        }
        #pragma unroll
        for (int i = 0; i < 4; ++i)
            #pragma unroll
            for (int j = 0; j < 4; ++j)
                acc[i][j] = __builtin_amdgcn_mfma_f32_16x16x32_f16(
                    af[i], bf[j], acc[i][j], 0, 0, 0);
        __syncthreads();
    }

    #pragma unroll
    for (int i = 0; i < 4; ++i) {
        int m = row0 + wm * 64 + i * 16 + (lane >> 4) * 4;
        #pragma unroll
        for (int j = 0; j < 4; ++j) {
            int c = col0 + wn * 64 + j * 16 + (lane & 15);
            #pragma unroll
            for (int r = 0; r < 4; ++r)
                C[(size_t)(m + r) * HD + c] = acc[i][j][r];
        }
    }
}

// ---------------------------------------------------------------------------
extern "C" void kernel_launch(void* const* d_in, const int* in_sizes, int n_in,
                              void* d_out, int out_size, void* d_ws, size_t ws_size,
                              hipStream_t stream)
{
    const float* x   = (const float*)d_in[0];   // (4,4096,2048)
    const float* Wq  = (const float*)d_in[1];   // (128,2048)
    const float* Wk  = (const float*)d_in[2];
    const float* Wv  = (const float*)d_in[3];
    const float* Wo  = (const float*)d_in[4];   // (2048,128)
    const float* Wgw = (const float*)d_in[5];   // (1,2048)
    const float* Wgb = (const float*)d_in[6];   // (1,)
    const float* lb  = (const float*)d_in[7];   // (1,)
    float* out = (float*)d_out;                 // 16384*2048 + 1

    // workspace layout (16B-aligned throughout)
    float* q    = (float*)d_ws;                            // 2,097,152 f32
    float* kn   = q + (size_t)NTOK * MD;
    float* vn   = kn + (size_t)NTOK * MD;
    float* wg   = vn + (size_t)NTOK * MD;                  // 16384
    float* kaT  = wg + NTOK;                               // 8192
    float* vagg = kaT + MD * NCH;                          // 8192
    float* wstr = vagg + NCH * MD;                         // 64
    float* G    = wstr + 64;                               // 16384
    float* kpart = G + MD * MD;                            // 32768
    float* vpart = kpart + 256 * 128;                      // 32768
    float* wpart = vpart + 256 * 128;                      // 256
    _Float16* Wcath = (_Float16*)(wpart + 256);            // 786,432 fp16
    _Float16* Woh   = Wcath + 384 * HD;                    // 262,144 fp16
    _Float16* rsh16 = Woh + HD * MD;                       // 2,097,152 fp16

    convert_w_kernel<<<dim3(4096), dim3(256), 0, stream>>>(Wq, Wk, Wv, Wo, Wcath, Woh);
    gmat_kernel<<<dim3(128), dim3(128), 0, stream>>>(Wo, G);
    gemm_proj_mfma<<<dim3(NTOK / 128, 3), dim3(256), 0, stream>>>(
        x, Wcath, Wgw, Wgb, q, kn, vn, wg);
    normsig_kernel<<<dim3(NTOK / 4), dim3(256), 0, stream>>>(kn, vn);
    agg_part_kernel<<<dim3(256), dim3(256), 0, stream>>>(kn, vn, wg, kpart, vpart, wpart);
    agg_combine_kernel<<<dim3(NCH), dim3(128), 0, stream>>>(kpart, vpart, wpart, kaT, vagg, wstr);
    meanws_kernel<<<dim3(1), dim3(64), 0, stream>>>(wstr, out + (size_t)NTOK * HD);
    attn_kernel<<<dim3(NTOK / 4), dim3(256), 0, stream>>>(q, kaT, vagg, G, lb, rsh16);
    gemm_out_mfma<<<dim3(NTOK / 128, HD / 128), dim3(256), 0, stream>>>(rsh16, Woh, out);
}